// Round 12
// baseline (500.566 us; speedup 1.0000x reference)
//
#include <hip/hip_runtime.h>

#define NNODE 50000
#define NEDGE 600000
#define KDIN  239
#define DDIM  128
#define NTILES 3125           // 3125*16 == 50000 exactly
#define NBG   782             // one-shot gemm blocks: 782*4 waves >= 3125 tiles
#define HB     64             // histogram / scatter blocks
#define CH     9375           // edges per hist/scat block (64*9375 == 600000)
#define HSWB   12500          // hist bins per sweep (4 sweeps)
#define SSWB   4096           // scatter cursor bins per sweep (13 sweeps)
#define NBSCAN 1563           // 32-dst scan tiles (1563*32 >= 50000)

typedef _Float16 half8 __attribute__((ext_vector_type(8)));
typedef _Float16 half4 __attribute__((ext_vector_type(4)));
typedef __attribute__((ext_vector_type(4))) float f32x4;

__device__ __forceinline__ ushort f2h(float f){
  union { _Float16 h; ushort u; } c; c.h = (_Float16)f; return c.u;
}
// monotone float<->uint encoding for atomicMax on signed floats
__device__ __forceinline__ unsigned fenc(float f){
  union { float f; unsigned u; } v; v.f = f;
  return (v.u & 0x80000000u) ? ~v.u : (v.u | 0x80000000u);
}
__device__ __forceinline__ float fdec(unsigned k){
  union { unsigned u; float f; } v;
  v.u = (k & 0x80000000u) ? (k & 0x7FFFFFFFu) : ~k;
  return v.f;
}

// ---- prologue: LDS histogram (no global atomics) || weight transposes || zero gm ----
__global__ __launch_bounds__(256) void pre_k(
    const float* __restrict__ W_in, const float* __restrict__ W_gat, const float* __restrict__ W_h,
    ushort* __restrict__ BfA, ushort* __restrict__ BfB, ushort* __restrict__ BfC,
    const int* __restrict__ ei, int* __restrict__ partial, unsigned* __restrict__ gm)
{
  __shared__ int hbin[HSWB];                       // 50 KB (pre_k only)
  const int b = blockIdx.x, t = threadIdx.x;
  if (b < HB){                                     // per-block LDS histogram of dst
    const int e0 = b*CH, e1 = min(NEDGE, e0+CH);
    for (int s=0; s<4; ++s){
      const int lo = s*HSWB;
      for (int i=t; i<HSWB; i+=256) hbin[i] = 0;
      __syncthreads();
      for (int e=e0+t; e<e1; e+=256){
        int dst = min(max(ei[NEDGE+e],0), NNODE-1);
        int r = dst - lo;
        if ((unsigned)r < HSWB) atomicAdd(&hbin[r], 1);   // LDS atomic
      }
      __syncthreads();
      for (int i=t; i<HSWB; i+=256) partial[b*NNODE + lo + i] = hbin[i];
      __syncthreads();
    }
  } else if (b < HB + 128){                        // W_in [239,128] -> BfA[n=128][k=256]
    int idx = (b-HB)*256 + t; int n = idx >> 8, k = idx & 255;
    BfA[idx] = (k < KDIN) ? f2h(W_in[(size_t)k*DDIM + n]) : (ushort)0;
  } else if (b < HB + 192){                        // W_gat -> BfB[n][128]
    int idx = (b-HB-128)*256 + t; int n = idx >> 7, k = idx & 127;
    BfB[idx] = f2h(W_gat[(size_t)k*DDIM + n]);
  } else if (b < HB + 256){                        // W_h -> BfC[n][128]
    int idx = (b-HB-192)*256 + t; int n = idx >> 7, k = idx & 127;
    BfC[idx] = f2h(W_h[(size_t)k*DDIM + n]);
  } else {
    if (t < 3) gm[t] = 0;                          // [gmax_s, gmax_d, gtotal]
  }
}

// ---- one-shot MFMA GEMM (R10-proven): each wave computes ONE 16x128 tile ----
// AMODE 0: A = raw fp32 [M,239]; AMODE 1: A = f16 [M,128]
// EPI 0: leaky(.01)(v+bias) -> f16
// EPI 1: v -> f16 + row dots os/od + global max -> gm[0..1]
// EPI 2: h2=leaky(.01)(v+bias); y = h2@W_out + b_out -> outf fp32
// XW 1: blocks >= NBG run the 32-dst tiled scan (8 KB LDS)
// XW 2: blocks >= NBG run the LDS-cursor CSR scatter (16 KB LDS)
template<int KSTEPS, int EPI, int XW, int AMODE>
__global__ __launch_bounds__(256, 4) void gemm7_k(
    const float* __restrict__ Afp, const ushort* __restrict__ Af,
    const ushort* __restrict__ Btf, const float* __restrict__ bias,
    float* __restrict__ outf, ushort* __restrict__ outh,
    const float* __restrict__ vs, const float* __restrict__ vd,
    float* __restrict__ os, float* __restrict__ od, unsigned* __restrict__ gm,
    const int* __restrict__ ei, int* __restrict__ partial,
    int* __restrict__ offs, int* __restrict__ degv, int* __restrict__ es)
{
  constexpr int Kpad = KSTEPS*32;
  if (XW == 1 && blockIdx.x >= NBG){               // tiled scan, 32 dsts/block
    __shared__ int T[HB*32];                       // 8 KB
    const int d0 = (blockIdx.x - NBG)*32;
    for (int it=threadIdx.x; it<HB*32; it+=256){
      const int bb = it>>5, d = it&31, dd = d0+d;
      T[it] = (dd < NNODE) ? partial[bb*NNODE + dd] : 0;
    }
    __syncthreads();
    if (threadIdx.x < 32){
      const int d = threadIdx.x;
      int deg = 0;
      #pragma unroll 8
      for (int bb=0;bb<HB;++bb) deg += T[bb*32+d];
      int incl = deg;
      #pragma unroll
      for (int off=1; off<32; off<<=1){ int v = __shfl_up(incl,off); if (d>=off) incl += v; }
      const int tot = __shfl(incl, 31);
      int base0 = 0;
      if (d==0) base0 = atomicAdd((int*)(gm+2), tot);  // tile base (any order ok)
      base0 = __shfl(base0, 0);
      const int dd = d0 + d;
      int run = base0 + incl - deg;
      if (dd < NNODE){ offs[dd] = run; degv[dd] = deg; }
      for (int bb=0;bb<HB;++bb){                   // per-histblock bases, in place
        if (dd < NNODE) partial[bb*NNODE + dd] = run;
        run += T[bb*32+d];
      }
    }
    return;
  }
  if (XW == 2 && blockIdx.x >= NBG){               // LDS-cursor CSR scatter
    __shared__ int cur[SSWB];                      // 16 KB
    const int hb = blockIdx.x - NBG;
    const int e0 = hb*CH, e1 = min(NEDGE, e0+CH);
    for (int s=0; s*SSWB < NNODE; ++s){
      const int lo = s*SSWB;
      for (int i=threadIdx.x; i<SSWB; i+=256){
        const int dd = lo + i;
        cur[i] = (dd < NNODE) ? partial[hb*NNODE + dd] : 0;
      }
      __syncthreads();
      for (int e=e0+threadIdx.x; e<e1; e+=256){    // edge chunk is L1/L2-hot on re-walks
        int dst = min(max(ei[NEDGE+e],0), NNODE-1);
        int r = dst - lo;
        if ((unsigned)r < SSWB){
          int src = min(max(ei[e],0), NNODE-1);
          int pos = atomicAdd(&cur[r], 1);         // LDS atomic
          es[pos] = src;                           // fire-and-forget 4B store
        }
      }
      __syncthreads();
    }
    return;
  }
  // ---- one-shot gemm path (zero LDS used) ----
  const int lane = threadIdx.x & 63;
  const int wave = threadIdx.x >> 6;
  const int q = lane >> 4, c = lane & 15;
  const int tile = blockIdx.x*4 + wave;
  if (tile >= NTILES) return;
  const int rowBase = tile*16;
  const int arow = rowBase + c;                    // always < NNODE (3125*16 exact)
  half8 af[KSTEPS];
  if (AMODE == 0){
    const float* __restrict__ ap = Afp + (size_t)arow*KDIN;
    #pragma unroll
    for (int s=0;s<KSTEPS;s++){
      #pragma unroll
      for (int i=0;i<8;i++){
        const int k = s*32 + q*8 + i;
        af[s][i] = (_Float16)((k < KDIN) ? ap[k] : 0.f);
      }
    }
  } else {
    const ushort* __restrict__ ap = Af + (size_t)arow*Kpad + q*8;
    #pragma unroll
    for (int s=0;s<KSTEPS;s++) af[s] = *(const half8*)(ap + s*32);
  }
  f32x4 acc[8];
  #pragma unroll
  for (int t=0;t<8;t++) acc[t] = (f32x4){0.f,0.f,0.f,0.f};
  #pragma unroll
  for (int s=0;s<KSTEPS;s++){
    #pragma unroll
    for (int t=0;t<8;t++){
      const half8 bf = *(const half8*)(Btf + (size_t)(16*t + c)*Kpad + s*32 + q*8);
      acc[t] = __builtin_amdgcn_mfma_f32_16x16x32_f16(af[s], bf, acc[t], 0,0,0);
    }
  }
  // epilogue: C/D layout col=lane&15, row=(lane>>4)*4+reg  [m89/m91-verified]
  float pr0[4] = {0,0,0,0}, pr1[4] = {0,0,0,0};
  #pragma unroll
  for (int t=0;t<8;t++){
    const int col = 16*t + c;
    const float bv = (EPI != 1) ? bias[col] : 0.f;
    float va=0.f, vb=0.f;
    if (EPI == 1){ va = vs[col]; vb = vd[col]; }
    if (EPI == 2){ va = vs[2*col]; vb = vs[2*col+1]; }
    #pragma unroll
    for (int r=0;r<4;r++){
      const int row = rowBase + q*4 + r;
      float v = acc[t][r] + bv;
      if (EPI != 1) v = (v >= 0.f) ? v : 0.01f*v;
      if (EPI == 0){
        outh[(size_t)row*DDIM + col] = f2h(v);
      } else if (EPI == 1){
        outh[(size_t)row*DDIM + col] = f2h(v);
        pr0[r] += v*va; pr1[r] += v*vb;
      } else {
        pr0[r] += v*va; pr1[r] += v*vb;
      }
    }
  }
  if (EPI >= 1){
    float lmax_s = -3.0e38f, lmax_d = -3.0e38f;
    #pragma unroll
    for (int r=0;r<4;r++){
      float s0 = pr0[r], s1 = pr1[r];
      s0 += __shfl_xor(s0,8); s1 += __shfl_xor(s1,8);
      s0 += __shfl_xor(s0,4); s1 += __shfl_xor(s1,4);
      s0 += __shfl_xor(s0,2); s1 += __shfl_xor(s1,2);
      s0 += __shfl_xor(s0,1); s1 += __shfl_xor(s1,1);
      if (EPI == 1){ lmax_s = fmaxf(lmax_s, s0); lmax_d = fmaxf(lmax_d, s1); }
      if (c == 0){
        const int row = rowBase + q*4 + r;
        if (EPI == 1){ os[row] = s0; od[row] = s1; }
        else { float2 y2; y2.x = s0 + vd[0]; y2.y = s1 + vd[1];
               *(float2*)&outf[(size_t)row*2] = y2; }
      }
    }
    if (EPI == 1){
      #pragma unroll
      for (int off=32; off>0; off>>=1){
        lmax_s = fmaxf(lmax_s, __shfl_xor(lmax_s, off));
        lmax_d = fmaxf(lmax_d, __shfl_xor(lmax_d, off));
      }
      if (lane == 0){ atomicMax(&gm[0], fenc(lmax_s)); atomicMax(&gm[1], fenc(lmax_d)); }
    }
  }
}

// ---- fused softmax+gather: og[dst] = softmax-agg(g f16) + b_gat -> f16 ----
// Each HALF-WAVE owns one dst independently (R8/R10-proven). 4 gather streams.
__global__ __launch_bounds__(256) void agg_k(const ushort* __restrict__ gf,
    const int* __restrict__ offs, const int* __restrict__ degv,
    const int* __restrict__ es,
    const float* __restrict__ a_src, const float* __restrict__ a_dst,
    const unsigned* __restrict__ gm, const float* __restrict__ b_gat,
    ushort* __restrict__ og)
{
  const int lane = threadIdx.x & 63;
  const int half = lane >> 5, li = lane & 31;
  const int dst = blockIdx.x*8 + (threadIdx.x >> 6)*2 + half;
  if (dst >= NNODE) return;
  float M = fdec(gm[0]) + fdec(gm[1]);
  M = (M >= 0.f) ? M : 0.2f*M;
  const int start = offs[dst];
  const int deg = degv[dst];
  const int* __restrict__ bin = es + start;
  const float ad = a_dst[dst];
  f32x4 a0={0,0,0,0}, a1={0,0,0,0}, a2={0,0,0,0}, a3={0,0,0,0};
  float w0s=0.f, w1s=0.f, w2s=0.f, w3s=0.f;
  int j = 0;
  for (; j+3 < deg; j += 4){
    const int i0=bin[j], i1=bin[j+1], i2=bin[j+2], i3=bin[j+3];
    float e0=a_src[i0]+ad; e0=(e0>=0.f)?e0:0.2f*e0;
    float e1=a_src[i1]+ad; e1=(e1>=0.f)?e1:0.2f*e1;
    float e2=a_src[i2]+ad; e2=(e2>=0.f)?e2:0.2f*e2;
    float e3=a_src[i3]+ad; e3=(e3>=0.f)?e3:0.2f*e3;
    const float w0=__expf(e0-M), w1=__expf(e1-M), w2=__expf(e2-M), w3=__expf(e3-M);
    const half4 g0 = *(const half4*)(gf + (size_t)i0*DDIM + li*4);
    const half4 g1 = *(const half4*)(gf + (size_t)i1*DDIM + li*4);
    const half4 g2 = *(const half4*)(gf + (size_t)i2*DDIM + li*4);
    const half4 g3 = *(const half4*)(gf + (size_t)i3*DDIM + li*4);
    #pragma unroll
    for (int i=0;i<4;i++){
      a0[i] += w0*(float)g0[i]; a1[i] += w1*(float)g1[i];
      a2[i] += w2*(float)g2[i]; a3[i] += w3*(float)g3[i];
    }
    w0s += w0; w1s += w1; w2s += w2; w3s += w3;
  }
  for (; j < deg; ++j){
    const int si = bin[j];
    float e0=a_src[si]+ad; e0=(e0>=0.f)?e0:0.2f*e0;
    const float w = __expf(e0-M);
    const half4 gv = *(const half4*)(gf + (size_t)si*DDIM + li*4);
    #pragma unroll
    for (int i=0;i<4;i++) a0[i] += w*(float)gv[i];
    w0s += w;
  }
  {                                                // self-loop (unconditional)
    float evs=a_src[dst]+ad; evs=(evs>=0.f)?evs:0.2f*evs;
    const float w = __expf(evs-M);
    const half4 gv = *(const half4*)(gf + (size_t)dst*DDIM + li*4);
    #pragma unroll
    for (int i=0;i<4;i++) a0[i] += w*(float)gv[i];
    w0s += w;
  }
  const float inv = 1.f/(w0s+w1s+w2s+w3s);         // >= w_self > 0
  const float4 bg = *(const float4*)&b_gat[li*4];
  ushort4 o;
  o.x = f2h((a0[0]+a1[0]+a2[0]+a3[0])*inv + bg.x);
  o.y = f2h((a0[1]+a1[1]+a2[1]+a3[1])*inv + bg.y);
  o.z = f2h((a0[2]+a1[2]+a2[2]+a3[2])*inv + bg.z);
  o.w = f2h((a0[3]+a1[3]+a2[3]+a3[3])*inv + bg.w);
  *(ushort4*)(og + (size_t)dst*DDIM + li*4) = o;
}

extern "C" void kernel_launch(void* const* d_in, const int* in_sizes, int n_in,
                              void* d_out, int out_size, void* d_ws, size_t ws_size,
                              hipStream_t stream)
{
  const float* x       = (const float*)d_in[0];
  const int*   ei      = (const int*)d_in[1];
  // d_in[2] = edge_type (unused by reference)
  const float* W_in    = (const float*)d_in[3];
  const float* b_in    = (const float*)d_in[4];
  const float* W_gat   = (const float*)d_in[5];
  const float* att_src = (const float*)d_in[6];
  const float* att_dst = (const float*)d_in[7];
  const float* b_gat   = (const float*)d_in[8];
  const float* W_h     = (const float*)d_in[9];
  const float* b_h     = (const float*)d_in[10];
  const float* W_out   = (const float*)d_in[11];
  const float* b_out   = (const float*)d_in[12];

  // workspace (~55 MB):
  char* ws = (char*)d_ws;
  ushort*   hf      = (ushort*)  (ws + 0);          // h f16 [N,128]    12.8 MB
  ushort*   gf      = (ushort*)  (ws + 12800000);   // g f16 [N,128]    12.8 MB
  ushort*   og      = (ushort*)  (ws + 25600000);   // og f16 [N,128]   12.8 MB
  int*      partial = (int*)     (ws + 38400000);   // [64][50000] = 12.8 MB (then bases)
  ushort*   BfA     = (ushort*)  (ws + 51200000);   // 128 KB
  ushort*   BfB     = (ushort*)  (ws + 51400000);   // 32 KB
  ushort*   BfC     = (ushort*)  (ws + 51500000);   // 32 KB
  int*      es      = (int*)     (ws + 51600000);   // CSR src, 2.4 MB
  int*      offs    = (int*)     (ws + 54000000);   // 200 KB
  int*      degv    = (int*)     (ws + 54200000);   // 200 KB
  float*    a_src   = (float*)   (ws + 54400000);
  float*    a_dst   = (float*)   (ws + 54600000);
  unsigned* gm      = (unsigned*)(ws + 54800000);   // [gmax_s, gmax_d, gtotal]

  // prologue: LDS histogram || weight transposes || zero gm
  pre_k<<<HB + 256 + 1, 256, 0, stream>>>(W_in, W_gat, W_h, BfA, BfB, BfC, ei, partial, gm);
  // gemmA: h = leaky(x@W_in + b_in) -> f16 (reads x fp32)  || tiled scan
  gemm7_k<8,0,1,0><<<NBG + NBSCAN, 256, 0, stream>>>(x, nullptr, BfA, b_in,
      nullptr, hf, nullptr, nullptr, nullptr, nullptr, gm, nullptr, partial, offs, degv, nullptr);
  // gemmB: g = h@W_gat -> f16 + a_src/a_dst + maxes  || LDS-cursor CSR scatter
  gemm7_k<4,1,2,1><<<NBG + HB, 256, 0, stream>>>(nullptr, hf, BfB, nullptr,
      nullptr, gf, att_src, att_dst, a_src, a_dst, gm, ei, partial, nullptr, nullptr, es);
  // fused softmax + gather + normalize
  agg_k<<<6250, 256, 0, stream>>>(gf, offs, degv, es, a_src, a_dst, gm, b_gat, og);
  // gemmC: y = leaky(og@W_h + b_h) @ W_out + b_out -> d_out fp32
  gemm7_k<4,2,0,1><<<NBG, 256, 0, stream>>>(nullptr, og, BfC, b_h,
      (float*)d_out, nullptr, W_out, b_out, nullptr, nullptr, nullptr, nullptr, nullptr, nullptr, nullptr, nullptr);
}

// Round 13
// 302.999 us; speedup vs baseline: 1.6520x; 1.6520x over previous
//
#include <hip/hip_runtime.h>

#define NNODE 50000
#define NEDGE 600000
#define KDIN  239
#define DDIM  128
#define NTILES 3125           // 3125*16 == 50000 exactly
#define NBG   782             // one-shot gemm blocks: 782*4 waves >= 3125 tiles
#define NBUCK 256             // coarse dst buckets
#define BSZ   196             // dsts per bucket (196*256 >= 50000)
#define CHP   2344            // edges per hist/partition block (256*2344 >= 600000)

typedef _Float16 half8 __attribute__((ext_vector_type(8)));
typedef _Float16 half4 __attribute__((ext_vector_type(4)));
typedef __attribute__((ext_vector_type(4))) float f32x4;

__device__ __forceinline__ ushort f2h(float f){
  union { _Float16 h; ushort u; } c; c.h = (_Float16)f; return c.u;
}
// monotone float<->uint encoding for atomicMax on signed floats
__device__ __forceinline__ unsigned fenc(float f){
  union { float f; unsigned u; } v; v.f = f;
  return (v.u & 0x80000000u) ? ~v.u : (v.u | 0x80000000u);
}
__device__ __forceinline__ float fdec(unsigned k){
  union { unsigned u; float f; } v;
  v.u = (k & 0x80000000u) ? (k & 0x7FFFFFFFu) : ~k;
  return v.f;
}

// ---- prologue: coarse LDS histogram (dst/196) || weight transposes || zero gm ----
__global__ __launch_bounds__(256) void pre_k(
    const float* __restrict__ W_in, const float* __restrict__ W_gat, const float* __restrict__ W_h,
    ushort* __restrict__ BfA, ushort* __restrict__ BfB, ushort* __restrict__ BfC,
    const int* __restrict__ ei, int* __restrict__ cpart, unsigned* __restrict__ gm)
{
  __shared__ int hb[NBUCK];
  const int b = blockIdx.x, t = threadIdx.x;
  if (b < NBUCK){                                  // coarse histogram, single sweep
    hb[t] = 0;
    __syncthreads();
    const int e0 = b*CHP, e1 = min(NEDGE, e0+CHP);
    for (int e=e0+t; e<e1; e+=256){
      int dst = min(max(ei[NEDGE+e],0), NNODE-1);
      atomicAdd(&hb[dst/BSZ], 1);                  // LDS atomic, 256 bins
    }
    __syncthreads();
    cpart[t*NBUCK + b] = hb[t];                    // bucket-major [bucket][block]
  } else if (b < NBUCK + 128){                     // W_in [239,128] -> BfA[n=128][k=256]
    int idx = (b-NBUCK)*256 + t; int n = idx >> 8, k = idx & 255;
    BfA[idx] = (k < KDIN) ? f2h(W_in[(size_t)k*DDIM + n]) : (ushort)0;
  } else if (b < NBUCK + 192){                     // W_gat -> BfB[n][128]
    int idx = (b-NBUCK-128)*256 + t; int n = idx >> 7, k = idx & 127;
    BfB[idx] = f2h(W_gat[(size_t)k*DDIM + n]);
  } else if (b < NBUCK + 256){                     // W_h -> BfC[n][128]
    int idx = (b-NBUCK-192)*256 + t; int n = idx >> 7, k = idx & 127;
    BfC[idx] = f2h(W_h[(size_t)k*DDIM + n]);
  } else {
    if (t < 2) gm[t] = 0;                          // [gmax_s, gmax_d]
  }
}

// ---- one-shot MFMA GEMM (R10-proven): each wave computes ONE 16x128 tile ----
// AMODE 0: A = raw fp32 [M,239]; AMODE 1: A = f16 [M,128]
// EPI 0: leaky(.01)(v+bias) -> f16
// EPI 1: v -> f16 + row dots os/od + global max -> gm[0..1]
// EPI 2: h2=leaky(.01)(v+bias); y = h2@W_out + b_out -> outf fp32
// XW 1: block NBG runs the coarse scan (cpart counts -> write bases, in place)
// XW 2: blocks >= NBG run the single-sweep LDS-cursor partition into pairs[]
template<int KSTEPS, int EPI, int XW, int AMODE>
__global__ __launch_bounds__(256, 4) void gemm8_k(
    const float* __restrict__ Afp, const ushort* __restrict__ Af,
    const ushort* __restrict__ Btf, const float* __restrict__ bias,
    float* __restrict__ outf, ushort* __restrict__ outh,
    const float* __restrict__ vs, const float* __restrict__ vd,
    float* __restrict__ os, float* __restrict__ od, unsigned* __restrict__ gm,
    const int* __restrict__ ei, int* __restrict__ cpart, int* __restrict__ pairs)
{
  constexpr int Kpad = KSTEPS*32;
  if (XW == 1 && blockIdx.x >= NBG){               // coarse scan, one block
    __shared__ int sc[NBUCK];
    const int t = threadIdx.x;                     // t = bucket id
    const int base = t*NBUCK;
    int sz = 0;
    for (int i=0;i<NBUCK;i++) sz += cpart[base+i]; // row sum (contiguous, L2-hot)
    sc[t] = sz;
    __syncthreads();
    #pragma unroll
    for (int off=1; off<NBUCK; off<<=1){           // Hillis-Steele inclusive scan
      int v = (t>=off) ? sc[t-off] : 0;
      __syncthreads();
      sc[t] += v;
      __syncthreads();
    }
    int run = sc[t] - sz;                          // exclusive: bucket base S[b]
    for (int i=0;i<NBUCK;i++){                     // counts -> per-(bucket,block) bases
      int c = cpart[base+i];
      cpart[base+i] = run;
      run += c;
    }
    return;
  }
  if (XW == 2 && blockIdx.x >= NBG){               // partition, single sweep
    __shared__ int cur[NBUCK];
    const int pb = blockIdx.x - NBG;
    cur[threadIdx.x] = cpart[threadIdx.x*NBUCK + pb];
    __syncthreads();
    const int e0 = pb*CHP, e1 = min(NEDGE, e0+CHP);
    for (int e=e0+threadIdx.x; e<e1; e+=256){
      int dst = min(max(ei[NEDGE+e],0), NNODE-1);
      int src = min(max(ei[e],0), NNODE-1);
      int bk = (unsigned)dst / BSZ;
      int pos = atomicAdd(&cur[bk], 1);            // LDS atomic
      pairs[pos] = src | ((dst - bk*BSZ) << 16);   // mostly-contiguous sub-range stores
    }
    return;
  }
  // ---- one-shot gemm path (R10-verbatim) ----
  const int lane = threadIdx.x & 63;
  const int wave = threadIdx.x >> 6;
  const int q = lane >> 4, c = lane & 15;
  const int tile = blockIdx.x*4 + wave;
  if (tile >= NTILES) return;
  const int rowBase = tile*16;
  const int arow = rowBase + c;                    // always < NNODE (3125*16 exact)
  half8 af[KSTEPS];
  if (AMODE == 0){
    const float* __restrict__ ap = Afp + (size_t)arow*KDIN;
    #pragma unroll
    for (int s=0;s<KSTEPS;s++){
      #pragma unroll
      for (int i=0;i<8;i++){
        const int k = s*32 + q*8 + i;
        af[s][i] = (_Float16)((k < KDIN) ? ap[k] : 0.f);
      }
    }
  } else {
    const ushort* __restrict__ ap = Af + (size_t)arow*Kpad + q*8;
    #pragma unroll
    for (int s=0;s<KSTEPS;s++) af[s] = *(const half8*)(ap + s*32);
  }
  f32x4 acc[8];
  #pragma unroll
  for (int t=0;t<8;t++) acc[t] = (f32x4){0.f,0.f,0.f,0.f};
  #pragma unroll
  for (int s=0;s<KSTEPS;s++){
    #pragma unroll
    for (int t=0;t<8;t++){
      const half8 bf = *(const half8*)(Btf + (size_t)(16*t + c)*Kpad + s*32 + q*8);
      acc[t] = __builtin_amdgcn_mfma_f32_16x16x32_f16(af[s], bf, acc[t], 0,0,0);
    }
  }
  // epilogue: C/D layout col=lane&15, row=(lane>>4)*4+reg  [m89/m91-verified]
  float pr0[4] = {0,0,0,0}, pr1[4] = {0,0,0,0};
  #pragma unroll
  for (int t=0;t<8;t++){
    const int col = 16*t + c;
    const float bv = (EPI != 1) ? bias[col] : 0.f;
    float va=0.f, vb=0.f;
    if (EPI == 1){ va = vs[col]; vb = vd[col]; }
    if (EPI == 2){ va = vs[2*col]; vb = vs[2*col+1]; }
    #pragma unroll
    for (int r=0;r<4;r++){
      const int row = rowBase + q*4 + r;
      float v = acc[t][r] + bv;
      if (EPI != 1) v = (v >= 0.f) ? v : 0.01f*v;
      if (EPI == 0){
        outh[(size_t)row*DDIM + col] = f2h(v);
      } else if (EPI == 1){
        outh[(size_t)row*DDIM + col] = f2h(v);
        pr0[r] += v*va; pr1[r] += v*vb;
      } else {
        pr0[r] += v*va; pr1[r] += v*vb;
      }
    }
  }
  if (EPI >= 1){
    float lmax_s = -3.0e38f, lmax_d = -3.0e38f;
    #pragma unroll
    for (int r=0;r<4;r++){
      float s0 = pr0[r], s1 = pr1[r];
      s0 += __shfl_xor(s0,8); s1 += __shfl_xor(s1,8);
      s0 += __shfl_xor(s0,4); s1 += __shfl_xor(s1,4);
      s0 += __shfl_xor(s0,2); s1 += __shfl_xor(s1,2);
      s0 += __shfl_xor(s0,1); s1 += __shfl_xor(s1,1);
      if (EPI == 1){ lmax_s = fmaxf(lmax_s, s0); lmax_d = fmaxf(lmax_d, s1); }
      if (c == 0){
        const int row = rowBase + q*4 + r;
        if (EPI == 1){ os[row] = s0; od[row] = s1; }
        else { float2 y2; y2.x = s0 + vd[0]; y2.y = s1 + vd[1];
               *(float2*)&outf[(size_t)row*2] = y2; }
      }
    }
    if (EPI == 1){
      #pragma unroll
      for (int off=32; off>0; off>>=1){
        lmax_s = fmaxf(lmax_s, __shfl_xor(lmax_s, off));
        lmax_d = fmaxf(lmax_d, __shfl_xor(lmax_d, off));
      }
      if (lane == 0){ atomicMax(&gm[0], fenc(lmax_s)); atomicMax(&gm[1], fenc(lmax_d)); }
    }
  }
}

// ---- fine CSR within one bucket: hist(196) + scan + scatter; emits offs/degv/es ----
__global__ __launch_bounds__(256) void fine_k(const int* __restrict__ pairs,
    const int* __restrict__ cpart, int* __restrict__ offs, int* __restrict__ degv,
    int* __restrict__ es)
{
  __shared__ int fh[256];
  __shared__ int sc[256];
  const int b = blockIdx.x, t = threadIdx.x;
  const int s0 = cpart[b*NBUCK];                   // bucket base S[b] (post-scan cpart)
  const int s1 = (b < NBUCK-1) ? cpart[(b+1)*NBUCK] : NEDGE;
  fh[t] = 0;
  __syncthreads();
  for (int i=s0+t; i<s1; i+=256)                   // contiguous, L2-hot
    atomicAdd(&fh[pairs[i] >> 16], 1);
  __syncthreads();
  const int deg = fh[t];
  sc[t] = deg;
  __syncthreads();
  #pragma unroll
  for (int off=1; off<256; off<<=1){               // inclusive scan
    int v = (t>=off) ? sc[t-off] : 0;
    __syncthreads();
    sc[t] += v;
    __syncthreads();
  }
  const int excl = sc[t] - deg;
  const int dst = b*BSZ + t;
  if (t < BSZ && dst < NNODE){ offs[dst] = s0 + excl; degv[dst] = deg; }
  fh[t] = s0 + excl;                               // becomes cursor
  __syncthreads();
  for (int i=s0+t; i<s1; i+=256){
    const int p = pairs[i];
    const int pos = atomicAdd(&fh[p >> 16], 1);    // LDS atomic
    es[pos] = p & 0xFFFF;                          // src (<50000 fits 16 bits)
  }
}

// ---- fused softmax+gather (R12-verbatim, passing): og = softmax-agg(g f16)+b_gat ----
__global__ __launch_bounds__(256) void agg_k(const ushort* __restrict__ gf,
    const int* __restrict__ offs, const int* __restrict__ degv,
    const int* __restrict__ es,
    const float* __restrict__ a_src, const float* __restrict__ a_dst,
    const unsigned* __restrict__ gm, const float* __restrict__ b_gat,
    ushort* __restrict__ og)
{
  const int lane = threadIdx.x & 63;
  const int half = lane >> 5, li = lane & 31;
  const int dst = blockIdx.x*8 + (threadIdx.x >> 6)*2 + half;
  if (dst >= NNODE) return;
  float M = fdec(gm[0]) + fdec(gm[1]);
  M = (M >= 0.f) ? M : 0.2f*M;
  const int start = offs[dst];
  const int deg = degv[dst];
  const int* __restrict__ bin = es + start;
  const float ad = a_dst[dst];
  f32x4 a0={0,0,0,0}, a1={0,0,0,0}, a2={0,0,0,0}, a3={0,0,0,0};
  float w0s=0.f, w1s=0.f, w2s=0.f, w3s=0.f;
  int j = 0;
  for (; j+3 < deg; j += 4){
    const int i0=bin[j], i1=bin[j+1], i2=bin[j+2], i3=bin[j+3];
    float e0=a_src[i0]+ad; e0=(e0>=0.f)?e0:0.2f*e0;
    float e1=a_src[i1]+ad; e1=(e1>=0.f)?e1:0.2f*e1;
    float e2=a_src[i2]+ad; e2=(e2>=0.f)?e2:0.2f*e2;
    float e3=a_src[i3]+ad; e3=(e3>=0.f)?e3:0.2f*e3;
    const float w0=__expf(e0-M), w1=__expf(e1-M), w2=__expf(e2-M), w3=__expf(e3-M);
    const half4 g0 = *(const half4*)(gf + (size_t)i0*DDIM + li*4);
    const half4 g1 = *(const half4*)(gf + (size_t)i1*DDIM + li*4);
    const half4 g2 = *(const half4*)(gf + (size_t)i2*DDIM + li*4);
    const half4 g3 = *(const half4*)(gf + (size_t)i3*DDIM + li*4);
    #pragma unroll
    for (int i=0;i<4;i++){
      a0[i] += w0*(float)g0[i]; a1[i] += w1*(float)g1[i];
      a2[i] += w2*(float)g2[i]; a3[i] += w3*(float)g3[i];
    }
    w0s += w0; w1s += w1; w2s += w2; w3s += w3;
  }
  for (; j < deg; ++j){
    const int si = bin[j];
    float e0=a_src[si]+ad; e0=(e0>=0.f)?e0:0.2f*e0;
    const float w = __expf(e0-M);
    const half4 gv = *(const half4*)(gf + (size_t)si*DDIM + li*4);
    #pragma unroll
    for (int i=0;i<4;i++) a0[i] += w*(float)gv[i];
    w0s += w;
  }
  {                                                // self-loop (unconditional)
    float evs=a_src[dst]+ad; evs=(evs>=0.f)?evs:0.2f*evs;
    const float w = __expf(evs-M);
    const half4 gv = *(const half4*)(gf + (size_t)dst*DDIM + li*4);
    #pragma unroll
    for (int i=0;i<4;i++) a0[i] += w*(float)gv[i];
    w0s += w;
  }
  const float inv = 1.f/(w0s+w1s+w2s+w3s);         // >= w_self > 0
  const float4 bg = *(const float4*)&b_gat[li*4];
  ushort4 o;
  o.x = f2h((a0[0]+a1[0]+a2[0]+a3[0])*inv + bg.x);
  o.y = f2h((a0[1]+a1[1]+a2[1]+a3[1])*inv + bg.y);
  o.z = f2h((a0[2]+a1[2]+a2[2]+a3[2])*inv + bg.z);
  o.w = f2h((a0[3]+a1[3]+a2[3]+a3[3])*inv + bg.w);
  *(ushort4*)(og + (size_t)dst*DDIM + li*4) = o;
}

extern "C" void kernel_launch(void* const* d_in, const int* in_sizes, int n_in,
                              void* d_out, int out_size, void* d_ws, size_t ws_size,
                              hipStream_t stream)
{
  const float* x       = (const float*)d_in[0];
  const int*   ei      = (const int*)d_in[1];
  // d_in[2] = edge_type (unused by reference)
  const float* W_in    = (const float*)d_in[3];
  const float* b_in    = (const float*)d_in[4];
  const float* W_gat   = (const float*)d_in[5];
  const float* att_src = (const float*)d_in[6];
  const float* att_dst = (const float*)d_in[7];
  const float* b_gat   = (const float*)d_in[8];
  const float* W_h     = (const float*)d_in[9];
  const float* b_h     = (const float*)d_in[10];
  const float* W_out   = (const float*)d_in[11];
  const float* b_out   = (const float*)d_in[12];

  // workspace (~45 MB):
  char* ws = (char*)d_ws;
  ushort*   hf     = (ushort*)  (ws + 0);          // h f16 [N,128]    12.8 MB
  ushort*   gf     = (ushort*)  (ws + 12800000);   // g f16 [N,128]    12.8 MB
  ushort*   og     = (ushort*)  (ws + 25600000);   // og f16 [N,128]   12.8 MB
  ushort*   BfA    = (ushort*)  (ws + 38400000);   // 128 KB
  ushort*   BfB    = (ushort*)  (ws + 38600000);   // 32 KB
  ushort*   BfC    = (ushort*)  (ws + 38700000);   // 32 KB
  int*      cpart  = (int*)     (ws + 38800000);   // [256][256] counts->bases, 256 KB
  int*      pairs  = (int*)     (ws + 39100000);   // bucket-major packed edges, 2.4 MB
  int*      es     = (int*)     (ws + 41500000);   // CSR src, 2.4 MB
  int*      offs   = (int*)     (ws + 43900000);   // 200 KB
  int*      degv   = (int*)     (ws + 44100000);   // 200 KB
  float*    a_src  = (float*)   (ws + 44300000);
  float*    a_dst  = (float*)   (ws + 44500000);
  unsigned* gm     = (unsigned*)(ws + 44700000);   // [gmax_s, gmax_d]

  // 1: coarse histogram || weight transposes || zero gm
  pre_k<<<NBUCK + 256 + 1, 256, 0, stream>>>(W_in, W_gat, W_h, BfA, BfB, BfC, ei, cpart, gm);
  // 2: gemmA (h = leaky(x@W_in+b_in) -> f16, reads x fp32) || coarse scan (1 block)
  gemm8_k<8,0,1,0><<<NBG + 1, 256, 0, stream>>>(x, nullptr, BfA, b_in,
      nullptr, hf, nullptr, nullptr, nullptr, nullptr, gm, nullptr, cpart, nullptr);
  // 3: gemmB (g = h@W_gat -> f16 + a_src/a_dst + maxes) || bucket partition (256 blocks)
  gemm8_k<4,1,2,1><<<NBG + NBUCK, 256, 0, stream>>>(nullptr, hf, BfB, nullptr,
      nullptr, gf, att_src, att_dst, a_src, a_dst, gm, ei, cpart, pairs);
  // 4: fine CSR per bucket (offs/degv/es)
  fine_k<<<NBUCK, 256, 0, stream>>>(pairs, cpart, offs, degv, es);
  // 5: fused softmax + gather + normalize
  agg_k<<<6250, 256, 0, stream>>>(gf, offs, degv, es, a_src, a_dst, gm, b_gat, og);
  // 6: gemmC: y = leaky(og@W_h + b_h) @ W_out + b_out -> d_out fp32
  gemm8_k<4,2,0,1><<<NBG, 256, 0, stream>>>(nullptr, og, BfC, b_h,
      (float*)d_out, nullptr, W_out, b_out, nullptr, nullptr, nullptr, nullptr, nullptr, nullptr);
}